// Round 9
// baseline (236.950 us; speedup 1.0000x reference)
//
#include <hip/hip_runtime.h>
#include <math.h>

#define N_RADIAL 8
#define N_PSEUDO 4
#define EMB_DIM 32
#define CUTOFF 5.0f
#define WIDTH 0.5f
#define SQRT3_4PI 0.48860251190291992f   /* sqrt(3/(4*pi)) */
#define INV_SQRT2 0.70710678118654752f
#define PI_F 3.14159265358979323846f

#define SLICE_SHIFT 6
#define SLICE_SZ 64             /* atoms per slice */
#define MAX_NSLICE 2048         /* LDS histogram capacity */
#define HIST_EPB 8192           /* edges per block, hist pass (centers only) */
#define SCAT_EPB 1024           /* edges per block, scatter pass (occupancy!) */

// ---------------------------------------------------------------------------
// G[tc][tn][n][k], k=0,1 only (v[:,:,2] is discarded by the reference).
// ---------------------------------------------------------------------------
__global__ void build_G_kernel(const float* __restrict__ W_species, // (4,4)
                               const float* __restrict__ Emb,       // (4,32)
                               const float* __restrict__ Wc,        // (32,3)
                               float* __restrict__ G) {
    int i = threadIdx.x;            // 256 threads, one per table entry
    int k  = i & 1;
    int n  = (i >> 1) & 7;
    int tn = (i >> 4) & 3;
    int tc = i >> 6;
    float acc = 0.0f;
    #pragma unroll
    for (int q = 0; q < N_PSEUDO; ++q) {
        int d = n * N_PSEUDO + q;
        acc += W_species[tn * N_PSEUDO + q] * Emb[tc * EMB_DIM + d] * Wc[d * 3 + k];
    }
    G[i] = acc;
}

// ---------------------------------------------------------------------------
// Per-edge math. Returns false if the edge is cut off.
// pr[j] = Y[m]*s[k] packed m-major: (Y0s0,Y0s1,Y1s0,Y1s1,Y2s0,Y2s1)
// ---------------------------------------------------------------------------
__device__ __forceinline__ bool edge_products(float vx, float vy, float vz,
                                              const float* __restrict__ Gp,
                                              float pr[6]) {
    float r = sqrtf(vx * vx + vy * vy + vz * vz);
    if (r >= CUTOFF) return false;

    float rinv = 1.0f / (r + 1e-10f);

    float t = (r - (CUTOFF - WIDTH)) / WIDTH;
    t = fminf(fmaxf(t, 0.0f), 1.0f);
    float fcut = 0.5f * (1.0f + cosf(PI_F * t));

    float theta = (PI_F / CUTOFF) * r;
    float s1, c1;
    sincosf(theta, &s1, &c1);
    float twoc  = 2.0f * c1;
    float sn_m1 = 0.0f;
    float sn    = s1;

    float s0 = 0.0f, s1a = 0.0f;
    #pragma unroll
    for (int n = 0; n < N_RADIAL; ++n) {
        s0  = fmaf(sn, Gp[n * 2 + 0], s0);
        s1a = fmaf(sn, Gp[n * 2 + 1], s1a);
        float nxt = twoc * sn - sn_m1;
        sn_m1 = sn;
        sn = nxt;
    }
    float coef = rinv * fcut;
    s0 *= coef; s1a *= coef;

    float Y0 = SQRT3_4PI * vy * rinv;
    float Y1 = SQRT3_4PI * vz * rinv;
    float Y2 = SQRT3_4PI * vx * rinv;

    pr[0] = Y0 * s0; pr[1] = Y0 * s1a;
    pr[2] = Y1 * s0; pr[3] = Y1 * s1a;
    pr[4] = Y2 * s0; pr[5] = Y2 * s1a;
    return true;
}

// ---------------------------------------------------------------------------
// Pass 1: count ALL edges per slice (centers only — no vecs, no sqrt).
// Over-counts vs the pass predicate: that's fine, sliceStart just reserves
// extra capacity; scatter packs passing edges from sliceStart[s] upward.
// ---------------------------------------------------------------------------
__global__ __launch_bounds__(256)
void hist_kernel(const int* __restrict__ centers,
                 unsigned int* __restrict__ ghist, int E, int nslice) {
    __shared__ unsigned int hist[MAX_NSLICE];
    for (int i = threadIdx.x; i < nslice; i += blockDim.x) hist[i] = 0u;
    __syncthreads();

    int beg = blockIdx.x * HIST_EPB;
    int end = min(beg + HIST_EPB, E);
    for (int e = beg + (int)threadIdx.x; e < end; e += (int)blockDim.x)
        atomicAdd(&hist[centers[e] >> SLICE_SHIFT], 1u);
    __syncthreads();

    for (int i = threadIdx.x; i < nslice; i += blockDim.x)
        if (hist[i]) atomicAdd(&ghist[i], hist[i]);
}

// ---------------------------------------------------------------------------
// Pass 2: exclusive scan on one 64-lane wave (chunked serial + shfl wave-scan).
// ---------------------------------------------------------------------------
__global__ void scan_kernel(const unsigned int* __restrict__ ghist,
                            unsigned int* __restrict__ sliceStart,
                            unsigned int* __restrict__ cursor, int nslice) {
    int lane = (int)threadIdx.x;        // 64 threads
    int chunk = (nslice + 63) / 64;
    int lo = lane * chunk;
    int hi = min(lo + chunk, nslice);

    unsigned int sum = 0;
    for (int i = lo; i < hi; ++i) sum += ghist[i];

    unsigned int inc = sum;
    #pragma unroll
    for (int d = 1; d < 64; d <<= 1) {
        unsigned int o = __shfl_up(inc, d, 64);
        if (lane >= d) inc += o;
    }
    unsigned int run = inc - sum;       // exclusive prefix of this chunk

    for (int i = lo; i < hi; ++i) {
        sliceStart[i] = run;
        cursor[i]     = run;
        run += ghist[i];
    }
    if (lane == 63) sliceStart[nslice] = run;   // grand total
}

// ---------------------------------------------------------------------------
// Pass 3: per-block local count (exact predicate) -> one cursor reservation
// per touched slice -> dense math -> 32B float4x2 payload scatter.
// ---------------------------------------------------------------------------
__global__ __launch_bounds__(256)
void scatter_kernel(const float* __restrict__ vecs,
                    const int*   __restrict__ centers,
                    const int*   __restrict__ neighbors,
                    const int*   __restrict__ species,
                    const float* __restrict__ G,
                    unsigned int* __restrict__ cursor,
                    float4*      __restrict__ payload,   // 2 float4 per entry
                    int E, int nslice) {
    __shared__ float Gs[256];
    __shared__ unsigned int hist[MAX_NSLICE];

    Gs[threadIdx.x] = G[threadIdx.x];
    for (int i = threadIdx.x; i < nslice; i += blockDim.x) hist[i] = 0u;
    __syncthreads();

    int beg = blockIdx.x * SCAT_EPB;
    int end = min(beg + SCAT_EPB, E);

    // local count with the exact pass predicate
    for (int e = beg + (int)threadIdx.x; e < end; e += (int)blockDim.x) {
        float vx = vecs[3 * e + 0], vy = vecs[3 * e + 1], vz = vecs[3 * e + 2];
        float r = sqrtf(vx * vx + vy * vy + vz * vz);
        if (r >= CUTOFF) continue;
        atomicAdd(&hist[centers[e] >> SLICE_SHIFT], 1u);
    }
    __syncthreads();

    // reserve global ranges; hist[s] becomes this block's running cursor
    for (int s = threadIdx.x; s < nslice; s += (int)blockDim.x) {
        unsigned int c = hist[s];
        hist[s] = c ? atomicAdd(&cursor[s], c) : 0u;
    }
    __syncthreads();

    // dense math + placement (vecs re-read is L1-hot: 12KB/block)
    for (int e = beg + (int)threadIdx.x; e < end; e += (int)blockDim.x) {
        float vx = vecs[3 * e + 0], vy = vecs[3 * e + 1], vz = vecs[3 * e + 2];
        int c = centers[e];
        int slice = c >> SLICE_SHIFT;
        int tc = species[c];
        int tn = species[neighbors[e]];
        const float* Gp = &Gs[((tc * 4 + tn) * 8) * 2];

        float pr[6];
        if (!edge_products(vx, vy, vz, Gp, pr)) continue;

        unsigned int pos = atomicAdd(&hist[slice], 1u);
        unsigned int lid = (unsigned int)(c & (SLICE_SZ - 1));
        payload[2 * (size_t)pos + 0] = make_float4(__uint_as_float(lid), pr[0], pr[1], pr[2]);
        payload[2 * (size_t)pos + 1] = make_float4(pr[3], pr[4], pr[5], 0.0f);
    }
}

// ---------------------------------------------------------------------------
// Pass 4: one block per slice. Contiguous payload reads, LDS f32 atomics
// (stride 9 => gcd(9,32)=1), cross-product epilogue, direct output write.
// ---------------------------------------------------------------------------
__global__ __launch_bounds__(256)
void accum_kernel(const float4* __restrict__ payload,
                  const unsigned int* __restrict__ sliceStart,
                  const unsigned int* __restrict__ cursor,   // final = packed end
                  float* __restrict__ out, int A) {
    __shared__ float acc[SLICE_SZ * 9];
    int s = blockIdx.x;

    for (int i = threadIdx.x; i < SLICE_SZ * 9; i += blockDim.x) acc[i] = 0.0f;
    __syncthreads();

    unsigned int beg = sliceStart[s], end = cursor[s];
    for (unsigned int i = beg + threadIdx.x; i < end; i += blockDim.x) {
        float4 pl0 = payload[2 * (size_t)i + 0];
        float4 pl1 = payload[2 * (size_t)i + 1];
        int lid = (int)__float_as_uint(pl0.x);
        float* ap = &acc[lid * 9];
        atomicAdd(ap + 0, pl0.y);
        atomicAdd(ap + 1, pl0.z);
        atomicAdd(ap + 2, pl0.w);
        atomicAdd(ap + 3, pl1.x);
        atomicAdd(ap + 4, pl1.y);
        atomicAdd(ap + 5, pl1.z);
    }
    __syncthreads();

    int a = s * SLICE_SZ + (int)threadIdx.x;
    if (threadIdx.x < SLICE_SZ && a < A) {
        const float* v = &acc[threadIdx.x * 9];
        float a0 = v[0], b0 = v[1];   // m=0 (y)
        float a1 = v[2], b1 = v[3];   // m=1 (z)
        float a2 = v[4], b2 = v[5];   // m=2 (x)

        float c0 = (a1 * b2 - a2 * b1) * INV_SQRT2;
        float c1 = (a2 * b0 - a0 * b2) * INV_SQRT2;
        float c2 = (a0 * b1 - a1 * b0) * INV_SQRT2;

        float* o = out + (size_t)a * 9;
        o[0] = a0; o[1] = b0; o[2] = c0;
        o[3] = a1; o[4] = b1; o[5] = c1;
        o[6] = a2; o[7] = b2; o[8] = c2;
    }
}

// ===========================================================================
// Fallback path (Round 6): packed fixed-point u64 global atomics. Used only
// if the workspace can't hold the sort payload.
// ===========================================================================
#define Q_INV 8192.0f
#define Q 1.220703125e-4
#define BIAS_ENC 131072.0f
#define ENC_MAX 262143.0f
#define FIELD_MASK 0x3FFFFFFULL

__global__ void edge_kernel_fb(const float* __restrict__ vecs,
                               const int* __restrict__ centers,
                               const int* __restrict__ neighbors,
                               const int* __restrict__ species,
                               const float* __restrict__ G,
                               unsigned long long* __restrict__ vacc, int E) {
    __shared__ float Gs[256];
    Gs[threadIdx.x] = G[threadIdx.x];
    __syncthreads();

    int e = blockIdx.x * blockDim.x + threadIdx.x;
    if (e >= E) return;

    float vx = vecs[3 * e + 0], vy = vecs[3 * e + 1], vz = vecs[3 * e + 2];
    int c = centers[e];
    int tc = species[c];
    int tn = species[neighbors[e]];
    const float* Gp = &Gs[((tc * 4 + tn) * 8) * 2];

    float pr[6];
    if (!edge_products(vx, vy, vz, Gp, pr)) return;

    unsigned long long* base = vacc + (size_t)c * 4;
    #pragma unroll
    for (int j = 0; j < 3; ++j) {
        float el = fminf(fmaxf(fmaf(pr[2 * j + 0], Q_INV, BIAS_ENC) + 0.5f, 0.0f), ENC_MAX);
        float eh = fminf(fmaxf(fmaf(pr[2 * j + 1], Q_INV, BIAS_ENC) + 0.5f, 0.0f), ENC_MAX);
        unsigned long long w = (1ULL << 52)
                             | ((unsigned long long)(unsigned int)eh << 26)
                             | (unsigned long long)(unsigned int)el;
        atomicAdd(base + j, w);
    }
}

__global__ void finalize_fb(const unsigned long long* __restrict__ vacc,
                            float* __restrict__ out, int A) {
    int a = blockIdx.x * blockDim.x + threadIdx.x;
    if (a >= A) return;

    const unsigned long long* w = vacc + (size_t)a * 4;
    double v[6];
    #pragma unroll
    for (int j = 0; j < 3; ++j) {
        unsigned long long x = w[j];
        double n = (double)(x >> 52);
        v[2 * j + 0] = (double)(x & FIELD_MASK)         * (double)Q - n * 16.0;
        v[2 * j + 1] = (double)((x >> 26) & FIELD_MASK) * (double)Q - n * 16.0;
    }
    float a0 = (float)v[0], b0 = (float)v[1];
    float a1 = (float)v[2], b1 = (float)v[3];
    float a2 = (float)v[4], b2 = (float)v[5];
    float c0 = (a1 * b2 - a2 * b1) * INV_SQRT2;
    float c1 = (a2 * b0 - a0 * b2) * INV_SQRT2;
    float c2 = (a0 * b1 - a1 * b0) * INV_SQRT2;
    float* o = out + (size_t)a * 9;
    o[0] = a0; o[1] = b0; o[2] = c0;
    o[3] = a1; o[4] = b1; o[5] = c1;
    o[6] = a2; o[7] = b2; o[8] = c2;
}

extern "C" void kernel_launch(void* const* d_in, const int* in_sizes, int n_in,
                              void* d_out, int out_size, void* d_ws, size_t ws_size,
                              hipStream_t stream) {
    const float* vecs      = (const float*)d_in[0];
    const float* W_species = (const float*)d_in[1];
    const float* Emb       = (const float*)d_in[2];
    const float* Wc        = (const float*)d_in[3];
    const int*   centers   = (const int*)d_in[4];
    const int*   neighbors = (const int*)d_in[5];
    const int*   species   = (const int*)d_in[6];

    int E = in_sizes[0] / 3;
    int A = in_sizes[6];

    int nslice = (A + SLICE_SZ - 1) / SLICE_SZ;

    // Workspace layout (sort path): payload | ghist | sliceStart | cursor | G
    size_t payloadBytes = (size_t)E * 8 * sizeof(float);
    size_t metaBytes    = (size_t)(3 * nslice + 1 + 256) * sizeof(float) + 256;
    bool sort_path = (nslice <= MAX_NSLICE) && (ws_size >= payloadBytes + metaBytes);

    if (sort_path) {
        float4*       payload    = (float4*)d_ws;
        unsigned int* ghist      = (unsigned int*)((char*)d_ws + payloadBytes);
        unsigned int* sliceStart = ghist + nslice;
        unsigned int* cursor     = sliceStart + (nslice + 1);
        float*        G          = (float*)(cursor + nslice);

        (void)hipMemsetAsync(ghist, 0, (size_t)nslice * sizeof(unsigned int), stream);
        build_G_kernel<<<1, 256, 0, stream>>>(W_species, Emb, Wc, G);

        int nbh = (E + HIST_EPB - 1) / HIST_EPB;
        hist_kernel<<<nbh, 256, 0, stream>>>(centers, ghist, E, nslice);
        scan_kernel<<<1, 64, 0, stream>>>(ghist, sliceStart, cursor, nslice);
        int nbs = (E + SCAT_EPB - 1) / SCAT_EPB;
        scatter_kernel<<<nbs, 256, 0, stream>>>(vecs, centers, neighbors, species,
                                                G, cursor, payload, E, nslice);
        accum_kernel<<<nslice, 256, 0, stream>>>(payload, sliceStart, cursor,
                                                 (float*)d_out, A);
    } else {
        unsigned long long* vacc = (unsigned long long*)d_ws;  // (A,4)
        float* G = (float*)(vacc + (size_t)A * 4);
        (void)hipMemsetAsync(vacc, 0, (size_t)A * 4 * sizeof(unsigned long long), stream);
        build_G_kernel<<<1, 256, 0, stream>>>(W_species, Emb, Wc, G);
        const int threads = 256;
        edge_kernel_fb<<<(E + threads - 1) / threads, threads, 0, stream>>>(
            vecs, centers, neighbors, species, G, vacc, E);
        finalize_fb<<<(A + threads - 1) / threads, threads, 0, stream>>>(
            vacc, (float*)d_out, A);
    }
}

// Round 10
// 164.807 us; speedup vs baseline: 1.4377x; 1.4377x over previous
//
#include <hip/hip_runtime.h>
#include <math.h>

#define N_RADIAL 8
#define N_PSEUDO 4
#define EMB_DIM 32
#define CUTOFF 5.0f
#define WIDTH 0.5f
#define SQRT3_4PI 0.48860251190291992f   /* sqrt(3/(4*pi)) */
#define INV_SQRT2 0.70710678118654752f
#define PI_F 3.14159265358979323846f

#define SLICE_SHIFT 7
#define SLICE_SZ 128            /* atoms per slice (Round-8 proven granularity) */
#define MAX_NSLICE 2048         /* LDS histogram capacity */
#define HIST_EPB 4096           /* edges per block, hist pass (centers only) */
#define SCAT_EPB 4096           /* edges per block, scatter pass */
#define SCAT_THREADS 1024       /* wide blocks: occupancy w/o fragmenting runs */
#define ACC_THREADS 1024

// ---------------------------------------------------------------------------
// G[tc][tn][n][k], k=0,1 only (v[:,:,2] is discarded by the reference).
// ---------------------------------------------------------------------------
__global__ void build_G_kernel(const float* __restrict__ W_species, // (4,4)
                               const float* __restrict__ Emb,       // (4,32)
                               const float* __restrict__ Wc,        // (32,3)
                               float* __restrict__ G) {
    int i = threadIdx.x;            // 256 threads, one per table entry
    int k  = i & 1;
    int n  = (i >> 1) & 7;
    int tn = (i >> 4) & 3;
    int tc = i >> 6;
    float acc = 0.0f;
    #pragma unroll
    for (int q = 0; q < N_PSEUDO; ++q) {
        int d = n * N_PSEUDO + q;
        acc += W_species[tn * N_PSEUDO + q] * Emb[tc * EMB_DIM + d] * Wc[d * 3 + k];
    }
    G[i] = acc;
}

// ---------------------------------------------------------------------------
// Per-edge math. Returns false if the edge is cut off.
// pr[j] = Y[m]*s[k] packed m-major: (Y0s0,Y0s1,Y1s0,Y1s1,Y2s0,Y2s1)
// ---------------------------------------------------------------------------
__device__ __forceinline__ bool edge_products(float vx, float vy, float vz,
                                              const float* __restrict__ Gp,
                                              float pr[6]) {
    float r = sqrtf(vx * vx + vy * vy + vz * vz);
    if (r >= CUTOFF) return false;

    float rinv = 1.0f / (r + 1e-10f);

    float t = (r - (CUTOFF - WIDTH)) / WIDTH;
    t = fminf(fmaxf(t, 0.0f), 1.0f);
    float fcut = 0.5f * (1.0f + cosf(PI_F * t));

    float theta = (PI_F / CUTOFF) * r;
    float s1, c1;
    sincosf(theta, &s1, &c1);
    float twoc  = 2.0f * c1;
    float sn_m1 = 0.0f;
    float sn    = s1;

    float s0 = 0.0f, s1a = 0.0f;
    #pragma unroll
    for (int n = 0; n < N_RADIAL; ++n) {
        s0  = fmaf(sn, Gp[n * 2 + 0], s0);
        s1a = fmaf(sn, Gp[n * 2 + 1], s1a);
        float nxt = twoc * sn - sn_m1;
        sn_m1 = sn;
        sn = nxt;
    }
    float coef = rinv * fcut;
    s0 *= coef; s1a *= coef;

    float Y0 = SQRT3_4PI * vy * rinv;
    float Y1 = SQRT3_4PI * vz * rinv;
    float Y2 = SQRT3_4PI * vx * rinv;

    pr[0] = Y0 * s0; pr[1] = Y0 * s1a;
    pr[2] = Y1 * s0; pr[3] = Y1 * s1a;
    pr[4] = Y2 * s0; pr[5] = Y2 * s1a;
    return true;
}

// ---------------------------------------------------------------------------
// Pass 1: count ALL edges per slice (centers only — no vecs, no sqrt).
// Over-counts vs the pass predicate: sliceStart just reserves capacity;
// scatter packs passing edges from sliceStart[s] upward.
// ---------------------------------------------------------------------------
__global__ __launch_bounds__(256)
void hist_kernel(const int* __restrict__ centers,
                 unsigned int* __restrict__ ghist, int E, int nslice) {
    __shared__ unsigned int hist[MAX_NSLICE];
    for (int i = threadIdx.x; i < nslice; i += blockDim.x) hist[i] = 0u;
    __syncthreads();

    int beg = blockIdx.x * HIST_EPB;
    int end = min(beg + HIST_EPB, E);
    for (int e = beg + (int)threadIdx.x; e < end; e += (int)blockDim.x)
        atomicAdd(&hist[centers[e] >> SLICE_SHIFT], 1u);
    __syncthreads();

    for (int i = threadIdx.x; i < nslice; i += blockDim.x)
        if (hist[i]) atomicAdd(&ghist[i], hist[i]);
}

// ---------------------------------------------------------------------------
// Pass 2: exclusive scan on one 64-lane wave (chunked serial + shfl wave-scan).
// ---------------------------------------------------------------------------
__global__ void scan_kernel(const unsigned int* __restrict__ ghist,
                            unsigned int* __restrict__ sliceStart,
                            unsigned int* __restrict__ cursor, int nslice) {
    int lane = (int)threadIdx.x;        // 64 threads
    int chunk = (nslice + 63) / 64;
    int lo = lane * chunk;
    int hi = min(lo + chunk, nslice);

    unsigned int sum = 0;
    for (int i = lo; i < hi; ++i) sum += ghist[i];

    unsigned int inc = sum;
    #pragma unroll
    for (int d = 1; d < 64; d <<= 1) {
        unsigned int o = __shfl_up(inc, d, 64);
        if (lane >= d) inc += o;
    }
    unsigned int run = inc - sum;       // exclusive prefix of this chunk

    for (int i = lo; i < hi; ++i) {
        sliceStart[i] = run;
        cursor[i]     = run;
        run += ghist[i];
    }
    if (lane == 63) sliceStart[nslice] = run;   // grand total
}

// ---------------------------------------------------------------------------
// Pass 3 (1024-thread blocks): per-block local count (exact predicate) ->
// one cursor reservation per touched slice -> dense math -> 32B payloads.
// EPB=4096 keeps runs ~9.7 entries (~310B) and reservations at ~190k total;
// 1024 threads gives ~30 waves/CU (Round 9 lesson: don't shrink EPB for
// occupancy — widen the block instead).
// ---------------------------------------------------------------------------
__global__ __launch_bounds__(SCAT_THREADS)
void scatter_kernel(const float* __restrict__ vecs,
                    const int*   __restrict__ centers,
                    const int*   __restrict__ neighbors,
                    const int*   __restrict__ species,
                    const float* __restrict__ G,
                    unsigned int* __restrict__ cursor,
                    float4*      __restrict__ payload,   // 2 float4 per entry
                    int E, int nslice) {
    __shared__ float Gs[256];
    __shared__ unsigned int hist[MAX_NSLICE];

    if (threadIdx.x < 256) Gs[threadIdx.x] = G[threadIdx.x];
    for (int i = threadIdx.x; i < nslice; i += blockDim.x) hist[i] = 0u;
    __syncthreads();

    int beg = blockIdx.x * SCAT_EPB;
    int end = min(beg + SCAT_EPB, E);

    // local count with the exact pass predicate
    for (int e = beg + (int)threadIdx.x; e < end; e += (int)blockDim.x) {
        float vx = vecs[3 * e + 0], vy = vecs[3 * e + 1], vz = vecs[3 * e + 2];
        float r = sqrtf(vx * vx + vy * vy + vz * vz);
        if (r >= CUTOFF) continue;
        atomicAdd(&hist[centers[e] >> SLICE_SHIFT], 1u);
    }
    __syncthreads();

    // reserve global ranges; hist[s] becomes this block's running cursor
    for (int s = threadIdx.x; s < nslice; s += (int)blockDim.x) {
        unsigned int c = hist[s];
        hist[s] = c ? atomicAdd(&cursor[s], c) : 0u;
    }
    __syncthreads();

    // dense math + placement (vecs re-read is L2-hot: 48KB/block)
    for (int e = beg + (int)threadIdx.x; e < end; e += (int)blockDim.x) {
        float vx = vecs[3 * e + 0], vy = vecs[3 * e + 1], vz = vecs[3 * e + 2];
        int c = centers[e];
        int slice = c >> SLICE_SHIFT;
        int tc = species[c];
        int tn = species[neighbors[e]];
        const float* Gp = &Gs[((tc * 4 + tn) * 8) * 2];

        float pr[6];
        if (!edge_products(vx, vy, vz, Gp, pr)) continue;

        unsigned int pos = atomicAdd(&hist[slice], 1u);
        unsigned int lid = (unsigned int)(c & (SLICE_SZ - 1));
        payload[2 * (size_t)pos + 0] = make_float4(__uint_as_float(lid), pr[0], pr[1], pr[2]);
        payload[2 * (size_t)pos + 1] = make_float4(pr[3], pr[4], pr[5], 0.0f);
    }
}

// ---------------------------------------------------------------------------
// Pass 4 (1024-thread blocks): one block per slice. Contiguous payload reads,
// LDS f32 atomics (stride 9 => gcd(9,32)=1), cross-product epilogue.
// ---------------------------------------------------------------------------
__global__ __launch_bounds__(ACC_THREADS)
void accum_kernel(const float4* __restrict__ payload,
                  const unsigned int* __restrict__ sliceStart,
                  const unsigned int* __restrict__ cursor,   // final = packed end
                  float* __restrict__ out, int A) {
    __shared__ float acc[SLICE_SZ * 9];
    int s = blockIdx.x;

    for (int i = threadIdx.x; i < SLICE_SZ * 9; i += blockDim.x) acc[i] = 0.0f;
    __syncthreads();

    unsigned int beg = sliceStart[s], end = cursor[s];
    for (unsigned int i = beg + threadIdx.x; i < end; i += blockDim.x) {
        float4 pl0 = payload[2 * (size_t)i + 0];
        float4 pl1 = payload[2 * (size_t)i + 1];
        int lid = (int)__float_as_uint(pl0.x);
        float* ap = &acc[lid * 9];
        atomicAdd(ap + 0, pl0.y);
        atomicAdd(ap + 1, pl0.z);
        atomicAdd(ap + 2, pl0.w);
        atomicAdd(ap + 3, pl1.x);
        atomicAdd(ap + 4, pl1.y);
        atomicAdd(ap + 5, pl1.z);
    }
    __syncthreads();

    int a = s * SLICE_SZ + (int)threadIdx.x;
    if (threadIdx.x < SLICE_SZ && a < A) {
        const float* v = &acc[threadIdx.x * 9];
        float a0 = v[0], b0 = v[1];   // m=0 (y)
        float a1 = v[2], b1 = v[3];   // m=1 (z)
        float a2 = v[4], b2 = v[5];   // m=2 (x)

        float c0 = (a1 * b2 - a2 * b1) * INV_SQRT2;
        float c1 = (a2 * b0 - a0 * b2) * INV_SQRT2;
        float c2 = (a0 * b1 - a1 * b0) * INV_SQRT2;

        float* o = out + (size_t)a * 9;
        o[0] = a0; o[1] = b0; o[2] = c0;
        o[3] = a1; o[4] = b1; o[5] = c1;
        o[6] = a2; o[7] = b2; o[8] = c2;
    }
}

// ===========================================================================
// Fallback path (Round 6): packed fixed-point u64 global atomics. Used only
// if the workspace can't hold the sort payload.
// ===========================================================================
#define Q_INV 8192.0f
#define Q 1.220703125e-4
#define BIAS_ENC 131072.0f
#define ENC_MAX 262143.0f
#define FIELD_MASK 0x3FFFFFFULL

__global__ void edge_kernel_fb(const float* __restrict__ vecs,
                               const int* __restrict__ centers,
                               const int* __restrict__ neighbors,
                               const int* __restrict__ species,
                               const float* __restrict__ G,
                               unsigned long long* __restrict__ vacc, int E) {
    __shared__ float Gs[256];
    Gs[threadIdx.x] = G[threadIdx.x];
    __syncthreads();

    int e = blockIdx.x * blockDim.x + threadIdx.x;
    if (e >= E) return;

    float vx = vecs[3 * e + 0], vy = vecs[3 * e + 1], vz = vecs[3 * e + 2];
    int c = centers[e];
    int tc = species[c];
    int tn = species[neighbors[e]];
    const float* Gp = &Gs[((tc * 4 + tn) * 8) * 2];

    float pr[6];
    if (!edge_products(vx, vy, vz, Gp, pr)) return;

    unsigned long long* base = vacc + (size_t)c * 4;
    #pragma unroll
    for (int j = 0; j < 3; ++j) {
        float el = fminf(fmaxf(fmaf(pr[2 * j + 0], Q_INV, BIAS_ENC) + 0.5f, 0.0f), ENC_MAX);
        float eh = fminf(fmaxf(fmaf(pr[2 * j + 1], Q_INV, BIAS_ENC) + 0.5f, 0.0f), ENC_MAX);
        unsigned long long w = (1ULL << 52)
                             | ((unsigned long long)(unsigned int)eh << 26)
                             | (unsigned long long)(unsigned int)el;
        atomicAdd(base + j, w);
    }
}

__global__ void finalize_fb(const unsigned long long* __restrict__ vacc,
                            float* __restrict__ out, int A) {
    int a = blockIdx.x * blockDim.x + threadIdx.x;
    if (a >= A) return;

    const unsigned long long* w = vacc + (size_t)a * 4;
    double v[6];
    #pragma unroll
    for (int j = 0; j < 3; ++j) {
        unsigned long long x = w[j];
        double n = (double)(x >> 52);
        v[2 * j + 0] = (double)(x & FIELD_MASK)         * (double)Q - n * 16.0;
        v[2 * j + 1] = (double)((x >> 26) & FIELD_MASK) * (double)Q - n * 16.0;
    }
    float a0 = (float)v[0], b0 = (float)v[1];
    float a1 = (float)v[2], b1 = (float)v[3];
    float a2 = (float)v[4], b2 = (float)v[5];
    float c0 = (a1 * b2 - a2 * b1) * INV_SQRT2;
    float c1 = (a2 * b0 - a0 * b2) * INV_SQRT2;
    float c2 = (a0 * b1 - a1 * b0) * INV_SQRT2;
    float* o = out + (size_t)a * 9;
    o[0] = a0; o[1] = b0; o[2] = c0;
    o[3] = a1; o[4] = b1; o[5] = c1;
    o[6] = a2; o[7] = b2; o[8] = c2;
}

extern "C" void kernel_launch(void* const* d_in, const int* in_sizes, int n_in,
                              void* d_out, int out_size, void* d_ws, size_t ws_size,
                              hipStream_t stream) {
    const float* vecs      = (const float*)d_in[0];
    const float* W_species = (const float*)d_in[1];
    const float* Emb       = (const float*)d_in[2];
    const float* Wc        = (const float*)d_in[3];
    const int*   centers   = (const int*)d_in[4];
    const int*   neighbors = (const int*)d_in[5];
    const int*   species   = (const int*)d_in[6];

    int E = in_sizes[0] / 3;
    int A = in_sizes[6];

    int nslice = (A + SLICE_SZ - 1) / SLICE_SZ;

    // Workspace layout (sort path): payload | ghist | sliceStart | cursor | G
    size_t payloadBytes = (size_t)E * 8 * sizeof(float);
    size_t metaBytes    = (size_t)(3 * nslice + 1 + 256) * sizeof(float) + 256;
    bool sort_path = (nslice <= MAX_NSLICE) && (ws_size >= payloadBytes + metaBytes);

    if (sort_path) {
        float4*       payload    = (float4*)d_ws;
        unsigned int* ghist      = (unsigned int*)((char*)d_ws + payloadBytes);
        unsigned int* sliceStart = ghist + nslice;
        unsigned int* cursor     = sliceStart + (nslice + 1);
        float*        G          = (float*)(cursor + nslice);

        (void)hipMemsetAsync(ghist, 0, (size_t)nslice * sizeof(unsigned int), stream);
        build_G_kernel<<<1, 256, 0, stream>>>(W_species, Emb, Wc, G);

        int nbh = (E + HIST_EPB - 1) / HIST_EPB;
        hist_kernel<<<nbh, 256, 0, stream>>>(centers, ghist, E, nslice);
        scan_kernel<<<1, 64, 0, stream>>>(ghist, sliceStart, cursor, nslice);
        int nbs = (E + SCAT_EPB - 1) / SCAT_EPB;
        scatter_kernel<<<nbs, SCAT_THREADS, 0, stream>>>(
            vecs, centers, neighbors, species, G, cursor, payload, E, nslice);
        accum_kernel<<<nslice, ACC_THREADS, 0, stream>>>(
            payload, sliceStart, cursor, (float*)d_out, A);
    } else {
        unsigned long long* vacc = (unsigned long long*)d_ws;  // (A,4)
        float* G = (float*)(vacc + (size_t)A * 4);
        (void)hipMemsetAsync(vacc, 0, (size_t)A * 4 * sizeof(unsigned long long), stream);
        build_G_kernel<<<1, 256, 0, stream>>>(W_species, Emb, Wc, G);
        const int threads = 256;
        edge_kernel_fb<<<(E + threads - 1) / threads, threads, 0, stream>>>(
            vecs, centers, neighbors, species, G, vacc, E);
        finalize_fb<<<(A + threads - 1) / threads, threads, 0, stream>>>(
            vacc, (float*)d_out, A);
    }
}

// Round 11
// 156.440 us; speedup vs baseline: 1.5146x; 1.0535x over previous
//
#include <hip/hip_runtime.h>
#include <math.h>

#define N_RADIAL 8
#define N_PSEUDO 4
#define EMB_DIM 32
#define CUTOFF 5.0f
#define WIDTH 0.5f
#define SQRT3_4PI 0.48860251190291992f   /* sqrt(3/(4*pi)) */
#define INV_SQRT2 0.70710678118654752f
#define PI_F 3.14159265358979323846f

#define SLICE_SHIFT 7
#define SLICE_SZ 128            /* atoms per slice */
#define MAX_NSLICE 2048         /* LDS histogram capacity */
#define HIST_EPB 4096           /* edges per block, hist pass (centers only) */
#define SCAT_EPB 4096           /* edges per block, scatter pass */
#define SCAT_THREADS 1024
#define ACC_THREADS 1024

// ---------------------------------------------------------------------------
// G[tc][tn][n][k], k=0,1 only (v[:,:,2] is discarded by the reference).
// ---------------------------------------------------------------------------
__global__ void build_G_kernel(const float* __restrict__ W_species, // (4,4)
                               const float* __restrict__ Emb,       // (4,32)
                               const float* __restrict__ Wc,        // (32,3)
                               float* __restrict__ G) {
    int i = threadIdx.x;            // 256 threads, one per table entry
    int k  = i & 1;
    int n  = (i >> 1) & 7;
    int tn = (i >> 4) & 3;
    int tc = i >> 6;
    float acc = 0.0f;
    #pragma unroll
    for (int q = 0; q < N_PSEUDO; ++q) {
        int d = n * N_PSEUDO + q;
        acc += W_species[tn * N_PSEUDO + q] * Emb[tc * EMB_DIM + d] * Wc[d * 3 + k];
    }
    G[i] = acc;
}

// ---------------------------------------------------------------------------
// Per-edge math. Returns false if the edge is cut off.
// pr[j] = Y[m]*s[k] packed m-major: (Y0s0,Y0s1,Y1s0,Y1s1,Y2s0,Y2s1)
// ---------------------------------------------------------------------------
__device__ __forceinline__ bool edge_products(float vx, float vy, float vz,
                                              const float* __restrict__ Gp,
                                              float pr[6]) {
    float r = sqrtf(vx * vx + vy * vy + vz * vz);
    if (r >= CUTOFF) return false;

    float rinv = 1.0f / (r + 1e-10f);

    float t = (r - (CUTOFF - WIDTH)) / WIDTH;
    t = fminf(fmaxf(t, 0.0f), 1.0f);
    float fcut = 0.5f * (1.0f + cosf(PI_F * t));

    float theta = (PI_F / CUTOFF) * r;
    float s1, c1;
    sincosf(theta, &s1, &c1);
    float twoc  = 2.0f * c1;
    float sn_m1 = 0.0f;
    float sn    = s1;

    float s0 = 0.0f, s1a = 0.0f;
    #pragma unroll
    for (int n = 0; n < N_RADIAL; ++n) {
        s0  = fmaf(sn, Gp[n * 2 + 0], s0);
        s1a = fmaf(sn, Gp[n * 2 + 1], s1a);
        float nxt = twoc * sn - sn_m1;
        sn_m1 = sn;
        sn = nxt;
    }
    float coef = rinv * fcut;
    s0 *= coef; s1a *= coef;

    float Y0 = SQRT3_4PI * vy * rinv;
    float Y1 = SQRT3_4PI * vz * rinv;
    float Y2 = SQRT3_4PI * vx * rinv;

    pr[0] = Y0 * s0; pr[1] = Y0 * s1a;
    pr[2] = Y1 * s0; pr[3] = Y1 * s1a;
    pr[4] = Y2 * s0; pr[5] = Y2 * s1a;
    return true;
}

// ---------------------------------------------------------------------------
// Pass 1: count ALL edges per slice (centers only — no vecs, no sqrt).
// Over-counts vs the pass predicate: sliceStart just reserves capacity.
// ---------------------------------------------------------------------------
__global__ __launch_bounds__(256)
void hist_kernel(const int* __restrict__ centers,
                 unsigned int* __restrict__ ghist, int E, int nslice) {
    __shared__ unsigned int hist[MAX_NSLICE];
    for (int i = threadIdx.x; i < nslice; i += blockDim.x) hist[i] = 0u;
    __syncthreads();

    int beg = blockIdx.x * HIST_EPB;
    int end = min(beg + HIST_EPB, E);
    for (int e = beg + (int)threadIdx.x; e < end; e += (int)blockDim.x)
        atomicAdd(&hist[centers[e] >> SLICE_SHIFT], 1u);
    __syncthreads();

    for (int i = threadIdx.x; i < nslice; i += blockDim.x)
        if (hist[i]) atomicAdd(&ghist[i], hist[i]);
}

// ---------------------------------------------------------------------------
// Pass 2: exclusive scan on one 64-lane wave (chunked serial + shfl wave-scan).
// ---------------------------------------------------------------------------
__global__ void scan_kernel(const unsigned int* __restrict__ ghist,
                            unsigned int* __restrict__ sliceStart,
                            unsigned int* __restrict__ cursor, int nslice) {
    int lane = (int)threadIdx.x;        // 64 threads
    int chunk = (nslice + 63) / 64;
    int lo = lane * chunk;
    int hi = min(lo + chunk, nslice);

    unsigned int sum = 0;
    for (int i = lo; i < hi; ++i) sum += ghist[i];

    unsigned int inc = sum;
    #pragma unroll
    for (int d = 1; d < 64; d <<= 1) {
        unsigned int o = __shfl_up(inc, d, 64);
        if (lane >= d) inc += o;
    }
    unsigned int run = inc - sum;       // exclusive prefix of this chunk

    for (int i = lo; i < hi; ++i) {
        sliceStart[i] = run;
        cursor[i]     = run;
        run += ghist[i];
    }
    if (lane == 63) sliceStart[nslice] = run;   // grand total
}

// ---------------------------------------------------------------------------
// Pass 3: predicate + 16B payload scatter — NO math here. Payload entry is
// one float4: (vx, vy, vz, meta{lid|tc<<7|tn<<9}). All per-edge math moved
// to accum (VALU there is ~0.4% busy — free), halving the scattered write
// bytes that both scatter (write) and accum (drain+read) pay for.
// ---------------------------------------------------------------------------
__global__ __launch_bounds__(SCAT_THREADS)
void scatter_kernel(const float* __restrict__ vecs,
                    const int*   __restrict__ centers,
                    const int*   __restrict__ neighbors,
                    const int*   __restrict__ species,
                    unsigned int* __restrict__ cursor,
                    float4*      __restrict__ payload,   // 1 float4 per entry
                    int E, int nslice) {
    __shared__ unsigned int hist[MAX_NSLICE];

    for (int i = threadIdx.x; i < nslice; i += blockDim.x) hist[i] = 0u;
    __syncthreads();

    int beg = blockIdx.x * SCAT_EPB;
    int end = min(beg + SCAT_EPB, E);

    // local count with the exact pass predicate
    for (int e = beg + (int)threadIdx.x; e < end; e += (int)blockDim.x) {
        float vx = vecs[3 * e + 0], vy = vecs[3 * e + 1], vz = vecs[3 * e + 2];
        float r = sqrtf(vx * vx + vy * vy + vz * vz);
        if (r >= CUTOFF) continue;
        atomicAdd(&hist[centers[e] >> SLICE_SHIFT], 1u);
    }
    __syncthreads();

    // reserve global ranges; hist[s] becomes this block's running cursor
    for (int s = threadIdx.x; s < nslice; s += (int)blockDim.x) {
        unsigned int c = hist[s];
        hist[s] = c ? atomicAdd(&cursor[s], c) : 0u;
    }
    __syncthreads();

    // placement (vecs re-read is cache-hot)
    for (int e = beg + (int)threadIdx.x; e < end; e += (int)blockDim.x) {
        float vx = vecs[3 * e + 0], vy = vecs[3 * e + 1], vz = vecs[3 * e + 2];
        float r = sqrtf(vx * vx + vy * vy + vz * vz);
        if (r >= CUTOFF) continue;

        int c = centers[e];
        unsigned int tc = (unsigned int)species[c];
        unsigned int tn = (unsigned int)species[neighbors[e]];
        unsigned int meta = (unsigned int)(c & (SLICE_SZ - 1)) | (tc << 7) | (tn << 9);

        unsigned int pos = atomicAdd(&hist[c >> SLICE_SHIFT], 1u);
        payload[pos] = make_float4(vx, vy, vz, __uint_as_float(meta));
    }
}

// ---------------------------------------------------------------------------
// Pass 4: one block per slice. Contiguous 16B payload reads, full per-edge
// math (recomputed here), LDS f32 atomics (stride 9), cross-product epilogue.
// ---------------------------------------------------------------------------
__global__ __launch_bounds__(ACC_THREADS)
void accum_kernel(const float4* __restrict__ payload,
                  const unsigned int* __restrict__ sliceStart,
                  const unsigned int* __restrict__ cursor,   // final = packed end
                  const float* __restrict__ G,
                  float* __restrict__ out, int A) {
    __shared__ float Gs[256];
    __shared__ float acc[SLICE_SZ * 9];
    int s = blockIdx.x;

    if (threadIdx.x < 256) Gs[threadIdx.x] = G[threadIdx.x];
    for (int i = threadIdx.x; i < SLICE_SZ * 9; i += blockDim.x) acc[i] = 0.0f;
    __syncthreads();

    unsigned int beg = sliceStart[s], end = cursor[s];
    for (unsigned int i = beg + threadIdx.x; i < end; i += blockDim.x) {
        float4 pl = payload[i];
        unsigned int meta = __float_as_uint(pl.w);
        int lid = (int)(meta & (SLICE_SZ - 1));
        int tc  = (int)((meta >> 7) & 3);
        int tn  = (int)((meta >> 9) & 3);
        const float* Gp = &Gs[((tc * 4 + tn) * 8) * 2];

        float pr[6];
        edge_products(pl.x, pl.y, pl.z, Gp, pr);   // predicate already passed

        float* ap = &acc[lid * 9];
        atomicAdd(ap + 0, pr[0]);
        atomicAdd(ap + 1, pr[1]);
        atomicAdd(ap + 2, pr[2]);
        atomicAdd(ap + 3, pr[3]);
        atomicAdd(ap + 4, pr[4]);
        atomicAdd(ap + 5, pr[5]);
    }
    __syncthreads();

    int a = s * SLICE_SZ + (int)threadIdx.x;
    if (threadIdx.x < SLICE_SZ && a < A) {
        const float* v = &acc[threadIdx.x * 9];
        float a0 = v[0], b0 = v[1];   // m=0 (y)
        float a1 = v[2], b1 = v[3];   // m=1 (z)
        float a2 = v[4], b2 = v[5];   // m=2 (x)

        float c0 = (a1 * b2 - a2 * b1) * INV_SQRT2;
        float c1 = (a2 * b0 - a0 * b2) * INV_SQRT2;
        float c2 = (a0 * b1 - a1 * b0) * INV_SQRT2;

        float* o = out + (size_t)a * 9;
        o[0] = a0; o[1] = b0; o[2] = c0;
        o[3] = a1; o[4] = b1; o[5] = c1;
        o[6] = a2; o[7] = b2; o[8] = c2;
    }
}

// ===========================================================================
// Fallback path (Round 6): packed fixed-point u64 global atomics. Used only
// if the workspace can't hold the sort payload.
// ===========================================================================
#define Q_INV 8192.0f
#define Q 1.220703125e-4
#define BIAS_ENC 131072.0f
#define ENC_MAX 262143.0f
#define FIELD_MASK 0x3FFFFFFULL

__global__ void edge_kernel_fb(const float* __restrict__ vecs,
                               const int* __restrict__ centers,
                               const int* __restrict__ neighbors,
                               const int* __restrict__ species,
                               const float* __restrict__ G,
                               unsigned long long* __restrict__ vacc, int E) {
    __shared__ float Gs[256];
    Gs[threadIdx.x] = G[threadIdx.x];
    __syncthreads();

    int e = blockIdx.x * blockDim.x + threadIdx.x;
    if (e >= E) return;

    float vx = vecs[3 * e + 0], vy = vecs[3 * e + 1], vz = vecs[3 * e + 2];
    int c = centers[e];
    int tc = species[c];
    int tn = species[neighbors[e]];
    const float* Gp = &Gs[((tc * 4 + tn) * 8) * 2];

    float pr[6];
    if (!edge_products(vx, vy, vz, Gp, pr)) return;

    unsigned long long* base = vacc + (size_t)c * 4;
    #pragma unroll
    for (int j = 0; j < 3; ++j) {
        float el = fminf(fmaxf(fmaf(pr[2 * j + 0], Q_INV, BIAS_ENC) + 0.5f, 0.0f), ENC_MAX);
        float eh = fminf(fmaxf(fmaf(pr[2 * j + 1], Q_INV, BIAS_ENC) + 0.5f, 0.0f), ENC_MAX);
        unsigned long long w = (1ULL << 52)
                             | ((unsigned long long)(unsigned int)eh << 26)
                             | (unsigned long long)(unsigned int)el;
        atomicAdd(base + j, w);
    }
}

__global__ void finalize_fb(const unsigned long long* __restrict__ vacc,
                            float* __restrict__ out, int A) {
    int a = blockIdx.x * blockDim.x + threadIdx.x;
    if (a >= A) return;

    const unsigned long long* w = vacc + (size_t)a * 4;
    double v[6];
    #pragma unroll
    for (int j = 0; j < 3; ++j) {
        unsigned long long x = w[j];
        double n = (double)(x >> 52);
        v[2 * j + 0] = (double)(x & FIELD_MASK)         * (double)Q - n * 16.0;
        v[2 * j + 1] = (double)((x >> 26) & FIELD_MASK) * (double)Q - n * 16.0;
    }
    float a0 = (float)v[0], b0 = (float)v[1];
    float a1 = (float)v[2], b1 = (float)v[3];
    float a2 = (float)v[4], b2 = (float)v[5];
    float c0 = (a1 * b2 - a2 * b1) * INV_SQRT2;
    float c1 = (a2 * b0 - a0 * b2) * INV_SQRT2;
    float c2 = (a0 * b1 - a1 * b0) * INV_SQRT2;
    float* o = out + (size_t)a * 9;
    o[0] = a0; o[1] = b0; o[2] = c0;
    o[3] = a1; o[4] = b1; o[5] = c1;
    o[6] = a2; o[7] = b2; o[8] = c2;
}

extern "C" void kernel_launch(void* const* d_in, const int* in_sizes, int n_in,
                              void* d_out, int out_size, void* d_ws, size_t ws_size,
                              hipStream_t stream) {
    const float* vecs      = (const float*)d_in[0];
    const float* W_species = (const float*)d_in[1];
    const float* Emb       = (const float*)d_in[2];
    const float* Wc        = (const float*)d_in[3];
    const int*   centers   = (const int*)d_in[4];
    const int*   neighbors = (const int*)d_in[5];
    const int*   species   = (const int*)d_in[6];

    int E = in_sizes[0] / 3;
    int A = in_sizes[6];

    int nslice = (A + SLICE_SZ - 1) / SLICE_SZ;

    // Workspace layout (sort path): payload | ghist | sliceStart | cursor | G
    size_t payloadBytes = (size_t)E * 4 * sizeof(float);   // 16B per entry
    size_t metaBytes    = (size_t)(3 * nslice + 1 + 256) * sizeof(float) + 256;
    bool sort_path = (nslice <= MAX_NSLICE) && (ws_size >= payloadBytes + metaBytes);

    if (sort_path) {
        float4*       payload    = (float4*)d_ws;
        unsigned int* ghist      = (unsigned int*)((char*)d_ws + payloadBytes);
        unsigned int* sliceStart = ghist + nslice;
        unsigned int* cursor     = sliceStart + (nslice + 1);
        float*        G          = (float*)(cursor + nslice);

        (void)hipMemsetAsync(ghist, 0, (size_t)nslice * sizeof(unsigned int), stream);
        build_G_kernel<<<1, 256, 0, stream>>>(W_species, Emb, Wc, G);

        int nbh = (E + HIST_EPB - 1) / HIST_EPB;
        hist_kernel<<<nbh, 256, 0, stream>>>(centers, ghist, E, nslice);
        scan_kernel<<<1, 64, 0, stream>>>(ghist, sliceStart, cursor, nslice);
        int nbs = (E + SCAT_EPB - 1) / SCAT_EPB;
        scatter_kernel<<<nbs, SCAT_THREADS, 0, stream>>>(
            vecs, centers, neighbors, species, cursor, payload, E, nslice);
        accum_kernel<<<nslice, ACC_THREADS, 0, stream>>>(
            payload, sliceStart, cursor, G, (float*)d_out, A);
    } else {
        unsigned long long* vacc = (unsigned long long*)d_ws;  // (A,4)
        float* G = (float*)(vacc + (size_t)A * 4);
        (void)hipMemsetAsync(vacc, 0, (size_t)A * 4 * sizeof(unsigned long long), stream);
        build_G_kernel<<<1, 256, 0, stream>>>(W_species, Emb, Wc, G);
        const int threads = 256;
        edge_kernel_fb<<<(E + threads - 1) / threads, threads, 0, stream>>>(
            vecs, centers, neighbors, species, G, vacc, E);
        finalize_fb<<<(A + threads - 1) / threads, threads, 0, stream>>>(
            vacc, (float*)d_out, A);
    }
}